// Round 5
// baseline (391.402 us; speedup 1.0000x reference)
//
#include <hip/hip_runtime.h>
#include <math.h>

// LBP radius=1, n_points=8 on NCHW (16,64,224,224) f32.
// Round-5: rolling-window strip kernel, 8-px-wide, distance-2 row prefetch.
// Each thread owns an 8-wide x 16-tall strip. Finalized 3-row x10-col window
// rolls down (4 rotating slots F0-F3, all-static indexing); raw row loads are
// issued TWO compute phases before use (2 RawRow slots, 8 loads in flight):
// ~1760 cy of compute covers the ~900 cy HBM miss latency per wave, without
// relying on occupancy. __launch_bounds__(256,4) gives a 128-VGPR budget for
// the ~110-reg live set -- round-4's (256,6) capped at 80 VGPR and almost
// certainly spilled the window to scratch, which is the suspected reason the
// rolling window didn't beat the batch kernels.
// p=0,2,4,6 exact neighbor compares; p=1,3,5,7 bilinear diagonals (bit-exact
// vs numpy f32: per-term rounding, left-to-right sum, no FMA contraction).
// Mask build: v_cmp + v_addc_co_u32 (2 VALU/bit), verified bit-exact in R3.
#define HH 224
#define WW 224
#define PLANES (16 * 64)
#define STRIP_H 16
#define TILE_W 8
#define TILES_X (WW / TILE_W)                  // 28
#define STRIPS_Y (HH / STRIP_H)                // 14
#define STRIPS_PER_PLANE (TILES_X * STRIPS_Y)  // 392
#define TOTAL_THREADS (PLANES * STRIPS_PER_PLANE)  // 401,408

struct LbpWeights {
    float w1[4];
    float w3[4];
    float w5[4];
    float w7[4];
};

struct RawRow { float4 qa, qb; float l, r; };  // as-loaded, pre-select
struct Row    { float v[TILE_W + 2]; };        // finalized (zeros outside)

__global__ __launch_bounds__(256, 4) void lbp_kernel(const float* __restrict__ x,
                                                     float* __restrict__ out,
                                                     LbpWeights wt) {
    int tid = blockIdx.x * 256 + threadIdx.x;

    int plane = tid / STRIPS_PER_PLANE;
    int t = tid - plane * STRIPS_PER_PLANE;
    int tr = t / TILES_X;
    int tc = t - tr * TILES_X;
    int r0 = tr * STRIP_H, c0 = tc * TILE_W;

    const float* pb = x + (size_t)plane * (HH * WW);

    bool cm = (c0 > 0), cp = (c0 + TILE_W < WW);
    // Clamped-safe column offsets; out-of-image values are zero-selected, so
    // the address only has to be in-bounds.
    int cl_off = cm ? -1 : 0;
    int cr_off = cp ? TILE_W : TILE_W - 1;

    // Issue the 4 loads for image row rr (clamped address; selects deferred
    // so the loads stay in flight for two compute phases).
    auto issue = [&](RawRow& s, int rr) {
        int rrc = rr < 0 ? 0 : (rr > HH - 1 ? HH - 1 : rr);
        const float* rp = pb + rrc * WW + c0;
        s.qa = *(const float4*)rp;
        s.qb = *(const float4*)(rp + 4);
        s.l = rp[cl_off];
        s.r = rp[cr_off];
    };
    // Apply zero-selects (constant-0 padding semantics).
    auto finalize = [&](Row& f, const RawRow& s, int rr) {
        bool ok = (unsigned)rr < (unsigned)HH;
        f.v[1] = ok ? s.qa.x : 0.0f;
        f.v[2] = ok ? s.qa.y : 0.0f;
        f.v[3] = ok ? s.qa.z : 0.0f;
        f.v[4] = ok ? s.qa.w : 0.0f;
        f.v[5] = ok ? s.qb.x : 0.0f;
        f.v[6] = ok ? s.qb.y : 0.0f;
        f.v[7] = ok ? s.qb.z : 0.0f;
        f.v[8] = ok ? s.qb.w : 0.0f;
        f.v[0] = (ok && cm) ? s.l : 0.0f;
        f.v[TILE_W + 1] = (ok && cp) ? s.r : 0.0f;
    };
    // Compute one output row (8 px) from rows A (above), B (center), C (below).
    auto compute_row = [&](const Row& A, const Row& B, const Row& C, float* orow) {
        float res[TILE_W];
#pragma unroll
        for (int k = 0; k < TILE_W; k++) {
            float ctr = B.v[k + 1];
            float n00 = A.v[k], n01 = A.v[k + 1], n02 = A.v[k + 2];
            float n10 = B.v[k],                   n12 = B.v[k + 2];
            float n20 = C.v[k], n21 = C.v[k + 1], n22 = C.v[k + 2];

            float v1, v3, v5, v7;
            {
#pragma clang fp contract(off)
                // p=1: r0=-1,c0=0 -> (n01, n02, ctr, n12)
                v1 = ((wt.w1[0] * n01 + wt.w1[1] * n02) + wt.w1[2] * ctr) + wt.w1[3] * n12;
                // p=3: r0=-1,c0=-1 -> (n00, n01, n10, ctr)
                v3 = ((wt.w3[0] * n00 + wt.w3[1] * n01) + wt.w3[2] * n10) + wt.w3[3] * ctr;
                // p=5: r0=0,c0=-1 -> (n10, ctr, n20, n21)
                v5 = ((wt.w5[0] * n10 + wt.w5[1] * ctr) + wt.w5[2] * n20) + wt.w5[3] * n21;
                // p=7: r0=0,c0=0 -> (ctr, n12, n21, n22)
                v7 = ((wt.w7[0] * ctr + wt.w7[1] * n12) + wt.w7[2] * n21) + wt.w7[3] * n22;
            }

            // m = sum 2^p * (v_p >= ctr), MSB-first: m = 2m + cmp.
            unsigned m = 0u;
#define LBP_BIT(val)                                                   \
    asm("v_cmp_ge_f32 vcc, %1, %2\n\t"                                 \
        "v_addc_co_u32 %0, vcc, %0, %0, vcc"                           \
        : "+v"(m) : "v"(val), "v"(ctr) : "vcc")
            LBP_BIT(v7);   // p=7
            LBP_BIT(n21);  // p=6
            LBP_BIT(v5);   // p=5
            LBP_BIT(n10);  // p=4
            LBP_BIT(v3);   // p=3
            LBP_BIT(n01);  // p=2
            LBP_BIT(v1);   // p=1
            LBP_BIT(n12);  // p=0
#undef LBP_BIT
            res[k] = (float)m;
        }
        *(float4*)orow = make_float4(res[0], res[1], res[2], res[3]);
        *(float4*)(orow + 4) = make_float4(res[4], res[5], res[6], res[7]);
    };

    // Finalized-row slot for image row g is F[(g+1)%4].
    // Raw slot for image row g is {RA if g even, RB if g odd} (r0 is even).
    Row F0, F1, F2, F3;
    RawRow RA, RB;

    // Prologue: overlap the three immediate rows, then preload distance-2.
    {
        RawRow p0, p1, p2;
        issue(p0, r0 - 1);
        issue(p1, r0);
        issue(p2, r0 + 1);
        finalize(F0, p0, r0 - 1);
        finalize(F1, p1, r0);
        finalize(F2, p2, r0 + 1);
    }
    issue(RA, r0 + 2);  // even
    issue(RB, r0 + 3);  // odd

    float* ob = out + (size_t)plane * (HH * WW) + r0 * WW + c0;

#pragma unroll 1
    for (int rb = 0; rb < STRIP_H / 4; rb++) {
        int g = rb * 4;
        // phase 0 (row g):   finalize row g+2 (RA) -> F3; issue row g+4 -> RA
        finalize(F3, RA, r0 + g + 2);
        issue(RA, r0 + g + 4);
        compute_row(F0, F1, F2, ob + (g + 0) * WW);
        // phase 1 (row g+1): finalize row g+3 (RB) -> F0; issue row g+5 -> RB
        finalize(F0, RB, r0 + g + 3);
        issue(RB, r0 + g + 5);
        compute_row(F1, F2, F3, ob + (g + 1) * WW);
        // phase 2 (row g+2): finalize row g+4 (RA) -> F1; issue row g+6 -> RA
        finalize(F1, RA, r0 + g + 4);
        issue(RA, r0 + g + 6);
        compute_row(F2, F3, F0, ob + (g + 2) * WW);
        // phase 3 (row g+3): finalize row g+5 (RB) -> F2; issue row g+7 -> RB
        finalize(F2, RB, r0 + g + 5);
        issue(RB, r0 + g + 7);
        compute_row(F3, F0, F1, ob + (g + 3) * WW);
    }
}

extern "C" void kernel_launch(void* const* d_in, const int* in_sizes, int n_in,
                              void* d_out, int out_size, void* d_ws, size_t ws_size,
                              hipStream_t stream) {
    (void)in_sizes; (void)n_in; (void)d_ws; (void)ws_size; (void)out_size;
    const float* x = (const float*)d_in[0];
    float* out = (float*)d_out;

    // Replicate np.round(-R*sin(ang), 8) = rint(v*1e8)/1e8 in double; weights
    // are float64 products rounded to f32 (NEP-50 weak-scalar semantics).
    LbpWeights wt;
    float* slots[4] = {wt.w1, wt.w3, wt.w5, wt.w7};
    const int diag_p[4] = {1, 3, 5, 7};
    for (int i = 0; i < 4; i++) {
        int p = diag_p[i];
        double ang = (2.0 * M_PI * (double)p) / 8.0;
        double dr = rint(-sin(ang) * 1e8) / 1e8;
        double dc = rint( cos(ang) * 1e8) / 1e8;
        double r0 = floor(dr), c0 = floor(dc);
        double fr = dr - r0, fc = dc - c0;
        slots[i][0] = (float)((1.0 - fr) * (1.0 - fc));
        slots[i][1] = (float)((1.0 - fr) * fc);
        slots[i][2] = (float)(fr * (1.0 - fc));
        slots[i][3] = (float)(fr * fc);
    }

    const int block = 256;
    const int grid = TOTAL_THREADS / block;  // 1568, exact
    lbp_kernel<<<grid, block, 0, stream>>>(x, out, wt);
}